// Round 3
// baseline (1313.317 us; speedup 1.0000x reference)
//
#include <hip/hip_runtime.h>
#include <hip/hip_cooperative_groups.h>

namespace cg = cooperative_groups;

#define N_NODES 10242
#define NNZ_E   71694
// rows padded to multiple of 8, +64 slack for the cooperative row over-read
#define NNZ_PAD_MAX (NNZ_E + 7 * N_NODES + 64)
#define BT      32      // B*T
#define C_IN    16
#define K_S     20
#define C_OUT   32
#define F       512     // BT * C_IN
typedef unsigned short u16;
typedef unsigned int   u32;

#define RING_ELEMS ((size_t)N_NODES * F)    // f16 elems per ring slot, layout [n][bt*16+c]
#define RING_BYTES (RING_ELEMS * 2)         // ~10.5 MB

// fused persistent kernel geometry: 256 blocks x 1024 thr = 4096 waves, 1 block/CU
#define NBLK_F   256
#define TPB_F    1024
#define NWAVES_F (NBLK_F * (TPB_F / 64))    // 4096; 3*4096 >= N_NODES

typedef __attribute__((ext_vector_type(8)))  _Float16 half8;
typedef __attribute__((ext_vector_type(16))) float    float16;

__device__ __forceinline__ void unpack8h(uint4 u, float* f) {
    union { uint4 u; _Float16 h[8]; } v; v.u = u;
    #pragma unroll
    for (int i = 0; i < 8; ++i) f[i] = (float)v.h[i];
}
__device__ __forceinline__ uint4 pack8h(const float* f) {
    union { uint4 u; _Float16 h[8]; } v;
    #pragma unroll
    for (int i = 0; i < 8; ++i) v.h[i] = (_Float16)f[i];
    return v.u;
}
__device__ __forceinline__ u16 f2h(float f) {
    union { _Float16 h; u16 u; } v; v.h = (_Float16)f; return v.u;
}

// ---------------- parallel CSR build (5 small wide-grid kernels) -----------
// Determinism: scatter order is nondeterministic, but each row's (col,valbits)
// multiset is fixed; an in-row sort by (col, valbits) makes the final CSR —
// and hence the f32 accumulation order — fully deterministic. Rows padded to
// x8 with (col=0, val=0) entries (contribute exactly 0).

// zero cnt + build W fragments (independent work, one launch)
// B-fragments for v_mfma_f32_32x32x16_f16:
// lane L, reg j -> B[k=8*(L>>5)+j][col=L&31] = W[cout=col][c=k][k_cheb]
__global__ __launch_bounds__(256) void init_kernel(
        const float* __restrict__ W, int* __restrict__ cnt,
        u16* __restrict__ wtfrag) {
    int i = blockIdx.x * 256 + threadIdx.x;
    if (i < N_NODES) cnt[i] = 0;
    int w = i - N_NODES;
    if (w >= 0 && w < K_S * 64 * 8) {
        int j    = w & 7;
        int lane = (w >> 3) & 63;
        int k    = w >> 9;
        int cout = lane & 31;
        int c    = ((lane >> 5) << 3) + j;
        wtfrag[w] = f2h(W[cout * (C_IN * K_S) + c * K_S + k]);
    }
}

__global__ __launch_bounds__(256) void count_kernel(
        const int* __restrict__ erow, int* cnt) {
    int e = blockIdx.x * 256 + threadIdx.x;
    if (e < NNZ_E) atomicAdd(&cnt[erow[e]], 1);
}

// exclusive scan of x8-padded counts; single 256-thread block (tiny: ~10k adds)
__global__ __launch_bounds__(256) void scan_kernel(
        const int* __restrict__ cnt, int* row_ptr, int* cursor) {
    const int T = 256;
    const int chunk = (N_NODES + T - 1) / T;  // 41
    __shared__ int part[T];
    int t = threadIdx.x;
    int base = t * chunk;
    int s = 0;
    for (int i = 0; i < chunk; ++i) {
        int idx = base + i;
        if (idx < N_NODES) s += (cnt[idx] + 7) & ~7;
    }
    part[t] = s;
    __syncthreads();
    for (int off = 1; off < T; off <<= 1) {
        int v = (t >= off) ? part[t - off] : 0;
        __syncthreads();
        part[t] += v;
        __syncthreads();
    }
    int run = (t == 0) ? 0 : part[t - 1];
    for (int i = 0; i < chunk; ++i) {
        int idx = base + i;
        if (idx < N_NODES) {
            row_ptr[idx] = run;
            cursor[idx]  = run;
            run += (cnt[idx] + 7) & ~7;
        }
    }
    if (t == T - 1) row_ptr[N_NODES] = part[T - 1];
}

// scatter (col, valbits) pairs directly into cpack (no eidx indirection)
__global__ __launch_bounds__(256) void scatter_kernel(
        const int* __restrict__ erow, const int* __restrict__ ecol,
        const float* __restrict__ eval, int* cursor, int2* __restrict__ cpack) {
    int e = blockIdx.x * 256 + threadIdx.x;
    if (e < NNZ_E) {
        int p = atomicAdd(&cursor[erow[e]], 1);
        cpack[p] = make_int2(ecol[e], __float_as_int(eval[e]));
    }
}

// per-row insertion sort by (col, valbits) + x8 pad fill; one thread per row
__global__ __launch_bounds__(256) void finalize_kernel(
        const int* __restrict__ row_ptr, const int* __restrict__ cursor,
        int2* cpack) {
    int r = blockIdx.x * 256 + threadIdx.x;
    if (r >= N_NODES) return;
    int sbeg = row_ptr[r];
    int send = cursor[r];        // sbeg + real count
    int pend = row_ptr[r + 1];   // sbeg + padded count
    for (int i = sbeg + 1; i < send; ++i) {
        int2 key = cpack[i];
        int j = i - 1;
        while (j >= sbeg) {
            int2 q = cpack[j];
            bool gt = (q.x > key.x) || (q.x == key.x && (u32)q.y > (u32)key.y);
            if (!gt) break;
            cpack[j + 1] = q;
            --j;
        }
        cpack[j + 1] = key;
    }
    for (int p = send; p < pend; ++p) cpack[p] = make_int2(0, 0);
}

// ---------------- fused persistent chain (cooperative) ---------------------
// Each wave owns <=3 nodes across ALL steps. Per node per step:
//   gather-spmm -> y (row of T_k) -> write ring slot (k%3)
//   -> shfl-permute y into MFMA A-frag -> acc += A @ W_k   (proj fused, free)
// A-frag mapping (verified layouts): MFMA lane L wants T[bt=L&31][c=8*(L>>5)+j];
// spmm lane S holds T[bt=S>>1][c=8*(S&1)+j] => S = ((L&31)<<1)|(L>>5).

__device__ __forceinline__ void mfma_step(float16& acc, uint4 yp,
                                          const u16* __restrict__ wfk, int lane) {
    int S = ((lane & 31) << 1) | (lane >> 5);
    uint4 af;
    af.x = (u32)__shfl((int)yp.x, S, 64);
    af.y = (u32)__shfl((int)yp.y, S, 64);
    af.z = (u32)__shfl((int)yp.z, S, 64);
    af.w = (u32)__shfl((int)yp.w, S, 64);
    union { uint4 u; half8 h; } au, bu;
    au.u = af;
    bu.u = *(const uint4*)(wfk + lane * 8);
    acc = __builtin_amdgcn_mfma_f32_32x32x16_f16(au.h, bu.h, acc, 0, 0, 0);
}

// k=0: transform x (fp32) -> T0 row (f16), write slot0, accumulate proj k=0
__device__ __forceinline__ void xform_node(int n, int lane,
        const float* __restrict__ x, u16* __restrict__ dst0,
        const u16* __restrict__ wf0, float16& acc) {
    int bt = lane >> 1;
    int hc = (lane & 1) * 8;
    const float* xp = x + ((size_t)bt * N_NODES + n) * C_IN + hc;
    float4 f0 = *(const float4*)xp;
    float4 f1 = *(const float4*)(xp + 4);
    float y[8] = {f0.x, f0.y, f0.z, f0.w, f1.x, f1.y, f1.z, f1.w};
    uint4 yp = pack8h(y);
    ((uint4*)(dst0 + (size_t)n * F))[lane] = yp;
    mfma_step(acc, yp, wf0, lane);
}

// one Chebyshev step for one node: dst = alpha * L@srcB + beta * srcA
__device__ __forceinline__ void step_node(int n, int len, int2 my, int lane,
        const u16* __restrict__ srcB, const u16* __restrict__ srcA,
        u16* __restrict__ dst, float alpha, float beta,
        const u16* __restrict__ wfk, float16& acc) {
    float a[8] = {0,0,0,0,0,0,0,0};
    if (beta != 0.f) {
        uint4 ua = ((const uint4*)(srcA + (size_t)n * F))[lane];
        unpack8h(ua, a);
    }

    float acc0[8] = {0,0,0,0,0,0,0,0};
    float acc1[8] = {0,0,0,0,0,0,0,0};

    for (int e = 0; e < len; e += 8) {
        int c0 = __builtin_amdgcn_readlane(my.x, e + 0);
        int c1 = __builtin_amdgcn_readlane(my.x, e + 1);
        int c2 = __builtin_amdgcn_readlane(my.x, e + 2);
        int c3 = __builtin_amdgcn_readlane(my.x, e + 3);
        int c4 = __builtin_amdgcn_readlane(my.x, e + 4);
        int c5 = __builtin_amdgcn_readlane(my.x, e + 5);
        int c6 = __builtin_amdgcn_readlane(my.x, e + 6);
        int c7 = __builtin_amdgcn_readlane(my.x, e + 7);
        float v0 = __int_as_float(__builtin_amdgcn_readlane(my.y, e + 0));
        float v1 = __int_as_float(__builtin_amdgcn_readlane(my.y, e + 1));
        float v2 = __int_as_float(__builtin_amdgcn_readlane(my.y, e + 2));
        float v3 = __int_as_float(__builtin_amdgcn_readlane(my.y, e + 3));
        float v4 = __int_as_float(__builtin_amdgcn_readlane(my.y, e + 4));
        float v5 = __int_as_float(__builtin_amdgcn_readlane(my.y, e + 5));
        float v6 = __int_as_float(__builtin_amdgcn_readlane(my.y, e + 6));
        float v7 = __int_as_float(__builtin_amdgcn_readlane(my.y, e + 7));

        uint4 g0 = ((const uint4*)(srcB + (size_t)c0 * F))[lane];
        uint4 g1 = ((const uint4*)(srcB + (size_t)c1 * F))[lane];
        uint4 g2 = ((const uint4*)(srcB + (size_t)c2 * F))[lane];
        uint4 g3 = ((const uint4*)(srcB + (size_t)c3 * F))[lane];
        uint4 g4 = ((const uint4*)(srcB + (size_t)c4 * F))[lane];
        uint4 g5 = ((const uint4*)(srcB + (size_t)c5 * F))[lane];
        uint4 g6 = ((const uint4*)(srcB + (size_t)c6 * F))[lane];
        uint4 g7 = ((const uint4*)(srcB + (size_t)c7 * F))[lane];

        float b0[8], b1[8], b2[8], b3[8], b4[8], b5[8], b6[8], b7[8];
        unpack8h(g0, b0); unpack8h(g1, b1); unpack8h(g2, b2); unpack8h(g3, b3);
        unpack8h(g4, b4); unpack8h(g5, b5); unpack8h(g6, b6); unpack8h(g7, b7);

        #pragma unroll
        for (int i = 0; i < 8; ++i) {
            acc0[i] += v0 * b0[i];
            acc1[i] += v1 * b1[i];
            acc0[i] += v2 * b2[i];
            acc1[i] += v3 * b3[i];
            acc0[i] += v4 * b4[i];
            acc1[i] += v5 * b5[i];
            acc0[i] += v6 * b6[i];
            acc1[i] += v7 * b7[i];
        }
    }

    float y[8];
    #pragma unroll
    for (int i = 0; i < 8; ++i)
        y[i] = alpha * (acc0[i] + acc1[i]) + beta * a[i];

    uint4 yp = pack8h(y);
    ((uint4*)(dst + (size_t)n * F))[lane] = yp;
    mfma_step(acc, yp, wfk, lane);
}

__device__ __forceinline__ void write_out(int n, int lane, const float16& acc,
                                          float* __restrict__ out) {
    int col = lane & 31;
    int grp = lane >> 5;
    #pragma unroll
    for (int r = 0; r < 16; ++r) {
        int bt = (r & 3) + 8 * (r >> 2) + 4 * grp;
        out[((size_t)bt * N_NODES + n) * C_OUT + col] = acc[r];
    }
}

__global__ __launch_bounds__(1024, 4) void cheb_fused_kernel(
        const float* __restrict__ x,
        const int* __restrict__ row_ptr, const int2* __restrict__ cpack,
        const u16* __restrict__ wtfrag, u16* __restrict__ ring,
        float* __restrict__ out) {
    cg::grid_group grid = cg::this_grid();
    const int lane = threadIdx.x & 63;
    const int wid  = blockIdx.x * (TPB_F / 64) + (threadIdx.x >> 6);

    const int n0 = wid;                 // always < N_NODES (4096 <= 10242)
    const int n1 = wid + NWAVES_F;      // always < N_NODES (8191 max)
    const int n2 = wid + 2 * NWAVES_F;  // may be invalid
    const bool v2 = (n2 < N_NODES);

    // hoist CSR rows into registers for the whole chain
    int  l0 = row_ptr[n0 + 1] - row_ptr[n0];
    int  l1 = row_ptr[n1 + 1] - row_ptr[n1];
    int  l2 = v2 ? (row_ptr[n2 + 1] - row_ptr[n2]) : 0;
    int2 my0 = cpack[row_ptr[n0] + lane];
    int2 my1 = cpack[row_ptr[n1] + lane];
    int2 my2 = v2 ? cpack[row_ptr[n2] + lane] : make_int2(0, 0);

    float16 ac0 = {}, ac1 = {}, ac2 = {};

    // k = 0: transform + proj
    xform_node(n0, lane, x, ring, wtfrag, ac0);
    xform_node(n1, lane, x, ring, wtfrag, ac1);
    if (v2) xform_node(n2, lane, x, ring, wtfrag, ac2);
    grid.sync();

    for (int k = 1; k < K_S; ++k) {
        const u16* srcB = ring + (size_t)((k - 1) % 3) * RING_ELEMS;
        const u16* srcA = ring + (size_t)((k + 1) % 3) * RING_ELEMS;  // (k-2)%3; unread at k=1
        u16*       dst  = ring + (size_t)(k % 3) * RING_ELEMS;
        float alpha = (k == 1) ? 1.f : 2.f;
        float beta  = (k == 1) ? 0.f : -1.f;
        const u16* wfk = wtfrag + (size_t)k * 512;

        step_node(n0, l0, my0, lane, srcB, srcA, dst, alpha, beta, wfk, ac0);
        step_node(n1, l1, my1, lane, srcB, srcA, dst, alpha, beta, wfk, ac1);
        if (v2) step_node(n2, l2, my2, lane, srcB, srcA, dst, alpha, beta, wfk, ac2);
        grid.sync();
    }

    write_out(n0, lane, ac0, out);
    write_out(n1, lane, ac1, out);
    if (v2) write_out(n2, lane, ac2, out);
}

// ---------------- fallback (round-2 multi-launch path) ---------------------

__global__ __launch_bounds__(256) void transform_kernel(
        const float* __restrict__ x, u16* __restrict__ T0) {
    int g = blockIdx.x * 256 + threadIdx.x;   // over N*F
    int n   = g >> 9;
    int rem = g & 511;
    int bt  = rem >> 4;
    int c   = rem & 15;
    float v = x[((size_t)bt * N_NODES + n) * C_IN + c];
    T0[(size_t)n * F + rem] = f2h(v);
}

__global__ __launch_bounds__(256) void spmm_step_kernel(
        const u16* __restrict__ srcB, const u16* __restrict__ srcA,
        u16* __restrict__ dst,
        const int* __restrict__ row_ptr, const int2* __restrict__ cpack,
        float alpha, float beta) {
    const int lane = threadIdx.x & 63;
    const int n = (blockIdx.x << 2) + (threadIdx.x >> 6);
    if (n >= N_NODES) return;
    const int s = row_ptr[n];
    const int len = row_ptr[n + 1] - s;
    int2 my = cpack[s + lane];
    float16 dummy = {};
    (void)dummy;
    float a[8] = {0,0,0,0,0,0,0,0};
    if (beta != 0.f) {
        uint4 ua = ((const uint4*)(srcA + (size_t)n * F))[lane];
        unpack8h(ua, a);
    }
    float acc0[8] = {0,0,0,0,0,0,0,0};
    float acc1[8] = {0,0,0,0,0,0,0,0};
    for (int e = 0; e < len; e += 8) {
        int c0 = __builtin_amdgcn_readlane(my.x, e + 0);
        int c1 = __builtin_amdgcn_readlane(my.x, e + 1);
        int c2 = __builtin_amdgcn_readlane(my.x, e + 2);
        int c3 = __builtin_amdgcn_readlane(my.x, e + 3);
        int c4 = __builtin_amdgcn_readlane(my.x, e + 4);
        int c5 = __builtin_amdgcn_readlane(my.x, e + 5);
        int c6 = __builtin_amdgcn_readlane(my.x, e + 6);
        int c7 = __builtin_amdgcn_readlane(my.x, e + 7);
        float v0 = __int_as_float(__builtin_amdgcn_readlane(my.y, e + 0));
        float v1 = __int_as_float(__builtin_amdgcn_readlane(my.y, e + 1));
        float v2 = __int_as_float(__builtin_amdgcn_readlane(my.y, e + 2));
        float v3 = __int_as_float(__builtin_amdgcn_readlane(my.y, e + 3));
        float v4 = __int_as_float(__builtin_amdgcn_readlane(my.y, e + 4));
        float v5 = __int_as_float(__builtin_amdgcn_readlane(my.y, e + 5));
        float v6 = __int_as_float(__builtin_amdgcn_readlane(my.y, e + 6));
        float v7 = __int_as_float(__builtin_amdgcn_readlane(my.y, e + 7));
        uint4 g0 = ((const uint4*)(srcB + (size_t)c0 * F))[lane];
        uint4 g1 = ((const uint4*)(srcB + (size_t)c1 * F))[lane];
        uint4 g2 = ((const uint4*)(srcB + (size_t)c2 * F))[lane];
        uint4 g3 = ((const uint4*)(srcB + (size_t)c3 * F))[lane];
        uint4 g4 = ((const uint4*)(srcB + (size_t)c4 * F))[lane];
        uint4 g5 = ((const uint4*)(srcB + (size_t)c5 * F))[lane];
        uint4 g6 = ((const uint4*)(srcB + (size_t)c6 * F))[lane];
        uint4 g7 = ((const uint4*)(srcB + (size_t)c7 * F))[lane];
        float b0[8], b1[8], b2[8], b3[8], b4[8], b5[8], b6[8], b7[8];
        unpack8h(g0, b0); unpack8h(g1, b1); unpack8h(g2, b2); unpack8h(g3, b3);
        unpack8h(g4, b4); unpack8h(g5, b5); unpack8h(g6, b6); unpack8h(g7, b7);
        #pragma unroll
        for (int i = 0; i < 8; ++i) {
            acc0[i] += v0 * b0[i];
            acc1[i] += v1 * b1[i];
            acc0[i] += v2 * b2[i];
            acc1[i] += v3 * b3[i];
            acc0[i] += v4 * b4[i];
            acc1[i] += v5 * b5[i];
            acc0[i] += v6 * b6[i];
            acc1[i] += v7 * b7[i];
        }
    }
    float y[8];
    #pragma unroll
    for (int i = 0; i < 8; ++i)
        y[i] = alpha * (acc0[i] + acc1[i]) + beta * a[i];
    ((uint4*)(dst + (size_t)n * F))[lane] = pack8h(y);
}

__global__ __launch_bounds__(256) void proj_mfma_kernel(
        const u16* __restrict__ ring, int R, int k0, int kcnt,
        const u16* __restrict__ wtfrag, float* __restrict__ out, int accumulate) {
    const int lane = threadIdx.x & 63;
    const int n = (blockIdx.x << 2) + (threadIdx.x >> 6);
    if (n >= N_NODES) return;
    const int col = lane & 31;
    const int grp = lane >> 5;
    const size_t aoff = (size_t)n * F + (size_t)col * 16 + grp * 8;
    union U { uint4 u; half8 h; };
    float16 acc0 = {};
    float16 acc1 = {};
    int j = 0;
    for (; j + 2 <= kcnt; j += 2) {
        int ka = k0 + j, kb = k0 + j + 1;
        U a0, b0, a1, b1;
        a0.u = *(const uint4*)(ring + (size_t)(ka % R) * RING_ELEMS + aoff);
        b0.u = *(const uint4*)(wtfrag + (size_t)ka * 512 + lane * 8);
        a1.u = *(const uint4*)(ring + (size_t)(kb % R) * RING_ELEMS + aoff);
        b1.u = *(const uint4*)(wtfrag + (size_t)kb * 512 + lane * 8);
        acc0 = __builtin_amdgcn_mfma_f32_32x32x16_f16(a0.h, b0.h, acc0, 0, 0, 0);
        acc1 = __builtin_amdgcn_mfma_f32_32x32x16_f16(a1.h, b1.h, acc1, 0, 0, 0);
    }
    if (j < kcnt) {
        int ka = k0 + j;
        U a0, b0;
        a0.u = *(const uint4*)(ring + (size_t)(ka % R) * RING_ELEMS + aoff);
        b0.u = *(const uint4*)(wtfrag + (size_t)ka * 512 + lane * 8);
        acc0 = __builtin_amdgcn_mfma_f32_32x32x16_f16(a0.h, b0.h, acc0, 0, 0, 0);
    }
    #pragma unroll
    for (int r = 0; r < 16; ++r) {
        int bt = (r & 3) + 8 * (r >> 2) + 4 * grp;
        float* op = out + ((size_t)bt * N_NODES + n) * C_OUT + col;
        float val = acc0[r] + acc1[r];
        if (accumulate) *op += val;
        else            *op  = val;
    }
}

// ---------------- host launch ----------------

extern "C" void kernel_launch(void* const* d_in, const int* in_sizes, int n_in,
                              void* d_out, int out_size, void* d_ws, size_t ws_size,
                              hipStream_t stream) {
    const float* x    = (const float*)d_in[0];
    const int*   erow = (const int*)  d_in[1];
    const int*   ecol = (const int*)  d_in[2];
    const float* eval = (const float*)d_in[3];
    const float* W    = (const float*)d_in[4];
    float* out = (float*)d_out;

    char* ws = (char*)d_ws;
    size_t o = 0;
    auto alloc = [&](size_t bytes) -> char* {
        o = (o + 511) & ~(size_t)511;
        char* r = ws + o;
        o += bytes;
        return r;
    };
    int*   cnt     = (int*)  alloc((size_t)N_NODES * 4);
    int*   row_ptr = (int*)  alloc((size_t)(N_NODES + 1) * 4);
    int*   cursor  = (int*)  alloc((size_t)N_NODES * 4);
    int2*  cpack   = (int2*) alloc((size_t)NNZ_PAD_MAX * 8);
    u16*   wtfrag  = (u16*)  alloc((size_t)K_S * 512 * 2);

    o = (o + 511) & ~(size_t)511;
    int R = (int)((ws_size - o) / RING_BYTES);
    if (R > K_S) R = K_S;
    if (R < 3)  R = 3;
    u16* ring = (u16*)(ws + o);
    auto slot = [&](int k) -> u16* { return ring + (size_t)(k % R) * RING_ELEMS; };

    // CSR build: 5 parallel kernels
    init_kernel<<<(N_NODES + K_S * 512 + 255) / 256, 256, 0, stream>>>(W, cnt, wtfrag);
    count_kernel<<<(NNZ_E + 255) / 256, 256, 0, stream>>>(erow, cnt);
    scan_kernel<<<1, 256, 0, stream>>>(cnt, row_ptr, cursor);
    scatter_kernel<<<(NNZ_E + 255) / 256, 256, 0, stream>>>(erow, ecol, eval, cursor, cpack);
    finalize_kernel<<<(N_NODES + 255) / 256, 256, 0, stream>>>(row_ptr, cursor, cpack);

    // fused cooperative chain: transform + 19 steps + proj in ONE dispatch
    {
        const float* xa = x; const int* rpa = row_ptr; const int2* cpa = cpack;
        const u16* wfa = wtfrag; u16* ra = ring; float* oa = out;
        void* args[] = {(void*)&xa, (void*)&rpa, (void*)&cpa,
                        (void*)&wfa, (void*)&ra, (void*)&oa};
        hipError_t err = hipLaunchCooperativeKernel(
            (const void*)cheb_fused_kernel, dim3(NBLK_F), dim3(TPB_F),
            args, 0, stream);
        if (err == hipSuccess) return;
        (void)hipGetLastError();   // clear; fall through to multi-launch path
    }

    // fallback: round-2 multi-launch pipeline
    const int grid4 = (N_NODES + 3) / 4;
    int c0 = 0;
    auto maybe_pass = [&](int k_done) {
        int target = K_S - c0;
        if (target > R) target = R;
        if (target > 0 && (k_done - c0 + 1) == target) {
            proj_mfma_kernel<<<grid4, 256, 0, stream>>>(
                ring, R, c0, target, wtfrag, out, (c0 > 0) ? 1 : 0);
            c0 += target;
        }
    };

    transform_kernel<<<(int)(RING_ELEMS / 256), 256, 0, stream>>>(x, slot(0));
    maybe_pass(0);
    for (int k = 1; k < K_S; ++k) {
        const u16* srcB = slot(k - 1);
        const u16* srcA = (k >= 2) ? slot(k - 2) : slot(k - 1);
        float alpha = (k == 1) ? 1.f : 2.f;
        float beta  = (k == 1) ? 0.f : -1.f;
        spmm_step_kernel<<<grid4, 256, 0, stream>>>(
            srcB, srcA, slot(k), row_ptr, cpack, alpha, beta);
        maybe_pass(k);
    }
}

// Round 4
// 450.964 us; speedup vs baseline: 2.9122x; 2.9122x over previous
//
#include <hip/hip_runtime.h>

#define N_NODES 10242
#define NNZ_E   71694
// rows padded to multiple of 8, +64 slack
#define NNZ_PAD_MAX (NNZ_E + 7 * N_NODES + 64)
#define BT      32      // B*T
#define C_IN    16
#define K_S     20
#define C_OUT   32
#define F       512     // BT * C_IN
typedef unsigned short u16;
typedef unsigned int   u32;

#define RING_ELEMS ((size_t)N_NODES * F)    // f16 elems per ring slot, layout [n][bt*16+c]
#define RING_BYTES (RING_ELEMS * 2)         // ~10.5 MB

#define NSLICE  8                           // F column slices, one per XCD
#define SLICE_U16 (F / NSLICE)              // 64 u16 = 128 B per node-row slice

typedef __attribute__((ext_vector_type(8)))  _Float16 half8;
typedef __attribute__((ext_vector_type(16))) float    float16;

__device__ __forceinline__ void unpack8h(uint4 u, float* f) {
    union { uint4 u; _Float16 h[8]; } v; v.u = u;
    #pragma unroll
    for (int i = 0; i < 8; ++i) f[i] = (float)v.h[i];
}
__device__ __forceinline__ uint4 pack8h(const float* f) {
    union { uint4 u; _Float16 h[8]; } v;
    #pragma unroll
    for (int i = 0; i < 8; ++i) v.h[i] = (_Float16)f[i];
    return v.u;
}
__device__ __forceinline__ u16 f2h(float f) {
    union { _Float16 h; u16 u; } v; v.h = (_Float16)f; return v.u;
}

// ---------------- parallel CSR build (5 small wide-grid kernels) -----------
// Determinism: scatter order is nondeterministic, but each row's (col,valbits)
// multiset is fixed; in-row sort by (col, valbits) makes the final CSR — and
// hence the f32 accumulation order — fully deterministic. Rows padded to x8
// with (col=0, val=0) entries (contribute exactly 0).

__global__ __launch_bounds__(256) void init_kernel(
        const float* __restrict__ W, int* __restrict__ cnt,
        u16* __restrict__ wtfrag) {
    int i = blockIdx.x * 256 + threadIdx.x;
    if (i < N_NODES) cnt[i] = 0;
    int w = i - N_NODES;
    if (w >= 0 && w < K_S * 64 * 8) {
        // B-frag for v_mfma_f32_32x32x16_f16: lane L, reg j ->
        // B[k=8*(L>>5)+j][col=L&31] = W[cout=col][c=k][k_cheb]
        int j    = w & 7;
        int lane = (w >> 3) & 63;
        int k    = w >> 9;
        int cout = lane & 31;
        int c    = ((lane >> 5) << 3) + j;
        wtfrag[w] = f2h(W[cout * (C_IN * K_S) + c * K_S + k]);
    }
}

__global__ __launch_bounds__(256) void count_kernel(
        const int* __restrict__ erow, int* cnt) {
    int e = blockIdx.x * 256 + threadIdx.x;
    if (e < NNZ_E) atomicAdd(&cnt[erow[e]], 1);
}

__global__ __launch_bounds__(256) void scan_kernel(
        const int* __restrict__ cnt, int* row_ptr, int* cursor) {
    const int T = 256;
    const int chunk = (N_NODES + T - 1) / T;  // 41
    __shared__ int part[T];
    int t = threadIdx.x;
    int base = t * chunk;
    int s = 0;
    for (int i = 0; i < chunk; ++i) {
        int idx = base + i;
        if (idx < N_NODES) s += (cnt[idx] + 7) & ~7;
    }
    part[t] = s;
    __syncthreads();
    for (int off = 1; off < T; off <<= 1) {
        int v = (t >= off) ? part[t - off] : 0;
        __syncthreads();
        part[t] += v;
        __syncthreads();
    }
    int run = (t == 0) ? 0 : part[t - 1];
    for (int i = 0; i < chunk; ++i) {
        int idx = base + i;
        if (idx < N_NODES) {
            row_ptr[idx] = run;
            cursor[idx]  = run;
            run += (cnt[idx] + 7) & ~7;
        }
    }
    if (t == T - 1) row_ptr[N_NODES] = part[T - 1];
}

__global__ __launch_bounds__(256) void scatter_kernel(
        const int* __restrict__ erow, const int* __restrict__ ecol,
        const float* __restrict__ eval, int* cursor, int2* __restrict__ cpack) {
    int e = blockIdx.x * 256 + threadIdx.x;
    if (e < NNZ_E) {
        int p = atomicAdd(&cursor[erow[e]], 1);
        cpack[p] = make_int2(ecol[e], __float_as_int(eval[e]));
    }
}

__global__ __launch_bounds__(256) void finalize_kernel(
        const int* __restrict__ row_ptr, const int* __restrict__ cursor,
        int2* cpack) {
    int r = blockIdx.x * 256 + threadIdx.x;
    if (r >= N_NODES) return;
    int sbeg = row_ptr[r];
    int send = cursor[r];        // sbeg + real count
    int pend = row_ptr[r + 1];   // sbeg + padded count
    for (int i = sbeg + 1; i < send; ++i) {
        int2 key = cpack[i];
        int j = i - 1;
        while (j >= sbeg) {
            int2 q = cpack[j];
            bool gt = (q.x > key.x) || (q.x == key.x && (u32)q.y > (u32)key.y);
            if (!gt) break;
            cpack[j + 1] = q;
            --j;
        }
        cpack[j + 1] = key;
    }
    for (int p = send; p < pend; ++p) cpack[p] = make_int2(0, 0);
}

// ---------------- transform: x (fp32) -> ring slot 0 (f16) ----------------

__global__ __launch_bounds__(256) void transform_kernel(
        const float* __restrict__ x, u16* __restrict__ T0) {
    int g = blockIdx.x * 256 + threadIdx.x;   // over N*F
    int n   = g >> 9;
    int rem = g & 511;
    int bt  = rem >> 4;
    int c   = rem & 15;
    float v = x[((size_t)bt * N_NODES + n) * C_IN + c];
    T0[(size_t)n * F + rem] = f2h(v);
}

// ---------------- Chebyshev step, XCD-column-sliced ------------------------
// dst[:, slice] = alpha * L @ srcB[:, slice] + beta * srcA[:, slice]
// slice = blockIdx & 7 — rides the blockIdx%8 -> XCD round-robin mapping so
// each XCD only ever gathers ITS 1.3 MB column-slice of the slot: chip-wide
// fill = 10.5 MB/step (once per byte) instead of ~8x duplication. Mapping is
// a perf heuristic only; correctness is mapping-independent.
// 256 thr = 4 waves; wave handles 8 nodes (8-lane group each, 16 B/lane).
// (col,val) broadcast from the group's cpack lanes via ds_bpermute (__shfl).

__global__ __launch_bounds__(256) void spmm_slice_kernel(
        const u16* __restrict__ srcB, const u16* __restrict__ srcA,
        u16* __restrict__ dst,
        const int* __restrict__ row_ptr, const int2* __restrict__ cpack,
        float alpha, float beta) {
    const int slice = blockIdx.x & 7;
    const int chunk = blockIdx.x >> 3;
    const int wave  = threadIdx.x >> 6;
    const int lane  = threadIdx.x & 63;
    const int l     = lane & 7;                 // 16B sub-offset in 128B slice
    const int n     = chunk * 32 + wave * 8 + (lane >> 3);
    const bool valid = (n < N_NODES);

    const int s   = valid ? row_ptr[n] : 0;
    const int len = valid ? (row_ptr[n + 1] - s) : 0;   // padded, multiple of 8

    const size_t soff = (size_t)slice * SLICE_U16 + (size_t)l * 8;

    float a[8] = {0,0,0,0,0,0,0,0};
    if (beta != 0.f && valid) {
        uint4 ua = *(const uint4*)(srcA + (size_t)n * F + soff);
        unpack8h(ua, a);
    }

    float acc[8] = {0,0,0,0,0,0,0,0};
    const int gbase = lane & 56;                // group's lane base

    for (int c = 0; c * 8 < len; ++c) {         // group-divergent; exec-masked
        int2 my = cpack[s + c * 8 + l];         // pad entries are (0, 0.0f)
        int col[8]; float v[8];
        #pragma unroll
        for (int r = 0; r < 8; ++r) {
            col[r] = __shfl(my.x, gbase + r, 64);
            v[r]   = __int_as_float(__shfl(my.y, gbase + r, 64));
        }
        uint4 g0 = *(const uint4*)(srcB + (size_t)col[0] * F + soff);
        uint4 g1 = *(const uint4*)(srcB + (size_t)col[1] * F + soff);
        uint4 g2 = *(const uint4*)(srcB + (size_t)col[2] * F + soff);
        uint4 g3 = *(const uint4*)(srcB + (size_t)col[3] * F + soff);
        uint4 g4 = *(const uint4*)(srcB + (size_t)col[4] * F + soff);
        uint4 g5 = *(const uint4*)(srcB + (size_t)col[5] * F + soff);
        uint4 g6 = *(const uint4*)(srcB + (size_t)col[6] * F + soff);
        uint4 g7 = *(const uint4*)(srcB + (size_t)col[7] * F + soff);
        float b0[8], b1[8], b2[8], b3[8], b4[8], b5[8], b6[8], b7[8];
        unpack8h(g0, b0); unpack8h(g1, b1); unpack8h(g2, b2); unpack8h(g3, b3);
        unpack8h(g4, b4); unpack8h(g5, b5); unpack8h(g6, b6); unpack8h(g7, b7);
        #pragma unroll
        for (int i = 0; i < 8; ++i) {
            acc[i] += v[0] * b0[i];
            acc[i] += v[1] * b1[i];
            acc[i] += v[2] * b2[i];
            acc[i] += v[3] * b3[i];
            acc[i] += v[4] * b4[i];
            acc[i] += v[5] * b5[i];
            acc[i] += v[6] * b6[i];
            acc[i] += v[7] * b7[i];
        }
    }

    if (valid) {
        float y[8];
        #pragma unroll
        for (int i = 0; i < 8; ++i)
            y[i] = alpha * acc[i] + beta * a[i];
        *(uint4*)(dst + (size_t)n * F + soff) = pack8h(y);
    }
}

// ---------------- MFMA projection over a chunk (kcnt <= K_S), f16 ----------
// per wave: one node; tile M=32(bt) x N=32(cout), K=kcnt*16.
// A: m=L&31, kk=8*(L>>5)+j ; C/D: col=L&31, row=(reg&3)+8*(reg>>2)+4*(L>>5)

__global__ __launch_bounds__(256) void proj_mfma_kernel(
        const u16* __restrict__ ring, int R, int k0, int kcnt,
        const u16* __restrict__ wtfrag, float* __restrict__ out, int accumulate) {
    const int lane = threadIdx.x & 63;
    const int n = (blockIdx.x << 2) + (threadIdx.x >> 6);
    if (n >= N_NODES) return;
    const int col = lane & 31;
    const int grp = lane >> 5;
    const size_t aoff = (size_t)n * F + (size_t)col * 16 + grp * 8;

    union U { uint4 u; half8 h; };
    float16 acc0 = {};
    float16 acc1 = {};
    int j = 0;
    for (; j + 2 <= kcnt; j += 2) {
        int ka = k0 + j, kb = k0 + j + 1;
        U a0, b0, a1, b1;
        a0.u = *(const uint4*)(ring + (size_t)(ka % R) * RING_ELEMS + aoff);
        b0.u = *(const uint4*)(wtfrag + (size_t)ka * 512 + lane * 8);
        a1.u = *(const uint4*)(ring + (size_t)(kb % R) * RING_ELEMS + aoff);
        b1.u = *(const uint4*)(wtfrag + (size_t)kb * 512 + lane * 8);
        acc0 = __builtin_amdgcn_mfma_f32_32x32x16_f16(a0.h, b0.h, acc0, 0, 0, 0);
        acc1 = __builtin_amdgcn_mfma_f32_32x32x16_f16(a1.h, b1.h, acc1, 0, 0, 0);
    }
    if (j < kcnt) {
        int ka = k0 + j;
        U a0, b0;
        a0.u = *(const uint4*)(ring + (size_t)(ka % R) * RING_ELEMS + aoff);
        b0.u = *(const uint4*)(wtfrag + (size_t)ka * 512 + lane * 8);
        acc0 = __builtin_amdgcn_mfma_f32_32x32x16_f16(a0.h, b0.h, acc0, 0, 0, 0);
    }

    #pragma unroll
    for (int r = 0; r < 16; ++r) {
        int bt = (r & 3) + 8 * (r >> 2) + 4 * grp;
        float* op = out + ((size_t)bt * N_NODES + n) * C_OUT + col;
        float val = acc0[r] + acc1[r];
        if (accumulate) *op += val;
        else            *op  = val;
    }
}

// ---------------- host launch ----------------

extern "C" void kernel_launch(void* const* d_in, const int* in_sizes, int n_in,
                              void* d_out, int out_size, void* d_ws, size_t ws_size,
                              hipStream_t stream) {
    const float* x    = (const float*)d_in[0];
    const int*   erow = (const int*)  d_in[1];
    const int*   ecol = (const int*)  d_in[2];
    const float* eval = (const float*)d_in[3];
    const float* W    = (const float*)d_in[4];
    float* out = (float*)d_out;

    char* ws = (char*)d_ws;
    size_t o = 0;
    auto alloc = [&](size_t bytes) -> char* {
        o = (o + 511) & ~(size_t)511;
        char* r = ws + o;
        o += bytes;
        return r;
    };
    int*   cnt     = (int*)  alloc((size_t)N_NODES * 4);
    int*   row_ptr = (int*)  alloc((size_t)(N_NODES + 1) * 4);
    int*   cursor  = (int*)  alloc((size_t)N_NODES * 4);
    int2*  cpack   = (int2*) alloc((size_t)NNZ_PAD_MAX * 8);
    u16*   wtfrag  = (u16*)  alloc((size_t)K_S * 512 * 2);

    o = (o + 511) & ~(size_t)511;
    int R = (int)((ws_size - o) / RING_BYTES);
    if (R > K_S) R = K_S;
    if (R < 3)  R = 3;
    u16* ring = (u16*)(ws + o);
    auto slot = [&](int k) -> u16* { return ring + (size_t)(k % R) * RING_ELEMS; };

    // CSR build: 5 parallel kernels
    init_kernel<<<(N_NODES + K_S * 512 + 255) / 256, 256, 0, stream>>>(W, cnt, wtfrag);
    count_kernel<<<(NNZ_E + 255) / 256, 256, 0, stream>>>(erow, cnt);
    scan_kernel<<<1, 256, 0, stream>>>(cnt, row_ptr, cursor);
    scatter_kernel<<<(NNZ_E + 255) / 256, 256, 0, stream>>>(erow, ecol, eval, cursor, cpack);
    finalize_kernel<<<(N_NODES + 255) / 256, 256, 0, stream>>>(row_ptr, cursor, cpack);

    const int grid4  = (N_NODES + 3) / 4;                    // proj: 4 nodes/block
    const int gridsl = NSLICE * ((N_NODES + 31) / 32);       // spmm: 8 slices x node-chunks
    int c0 = 0;
    auto maybe_pass = [&](int k_done) {
        int target = K_S - c0;
        if (target > R) target = R;   // chunk == R safe (stream-ordered)
        if (target > 0 && (k_done - c0 + 1) == target) {
            proj_mfma_kernel<<<grid4, 256, 0, stream>>>(
                ring, R, c0, target, wtfrag, out, (c0 > 0) ? 1 : 0);
            c0 += target;
        }
    };

    // T0 -> slot 0
    transform_kernel<<<(int)(RING_ELEMS / 256), 256, 0, stream>>>(x, slot(0));
    maybe_pass(0);

    // T1 = L T0 ; Tk = 2 L T_{k-1} - T_{k-2}
    for (int k = 1; k < K_S; ++k) {
        const u16* srcB = slot(k - 1);
        const u16* srcA = (k >= 2) ? slot(k - 2) : slot(k - 1);  // unread when beta==0
        float alpha = (k == 1) ? 1.f : 2.f;
        float beta  = (k == 1) ? 0.f : -1.f;
        spmm_slice_kernel<<<gridsl, 256, 0, stream>>>(
            srcB, srcA, slot(k), row_ptr, cpack, alpha, beta);
        maybe_pass(k);
    }
}